// Round 1
// baseline (1714.561 us; speedup 1.0000x reference)
//
#include <hip/hip_runtime.h>
#include <math.h>

#define D_MODEL 1024
#define D_INNER 2048
#define DT_RANK 64
#define D_STATE 16
#define NBC 96   // DT_RANK + 2*D_STATE
#define BATCH 2
#define SEQ 1024
#define TOK (BATCH*SEQ)  // 2048

// ---------------- device helpers ----------------
__device__ __forceinline__ float softplus_f(float x) {
    return (x > 20.0f) ? x : log1pf(expf(x));
}
__device__ __forceinline__ float gelu_f(float x) {
    return 0.5f * x * (1.0f + erff(x * 0.70710678118654752f));
}
__device__ __forceinline__ float silu_f(float x) {
    return x / (1.0f + expf(-x));
}

// ---------------- LayerNorm: one block per row (D=1024, 256 thr, float4) ----------------
__global__ void ln_kernel(const float* __restrict__ x, const float* __restrict__ g,
                          const float* __restrict__ b, float* __restrict__ out) {
    int row = blockIdx.x;
    const float* xr = x + (size_t)row * D_MODEL;
    float* outr = out + (size_t)row * D_MODEL;
    int tid = threadIdx.x;
    float4 v = ((const float4*)xr)[tid];
    float s  = v.x + v.y + v.z + v.w;
    float sq = v.x*v.x + v.y*v.y + v.z*v.z + v.w*v.w;
    #pragma unroll
    for (int o = 32; o > 0; o >>= 1) {
        s  += __shfl_down(s,  o);
        sq += __shfl_down(sq, o);
    }
    __shared__ float ss[4], ssq[4];
    int wid = tid >> 6, lane = tid & 63;
    if (lane == 0) { ss[wid] = s; ssq[wid] = sq; }
    __syncthreads();
    if (tid == 0) {
        float a = 0.f, c = 0.f;
        for (int i = 0; i < 4; i++) { a += ss[i]; c += ssq[i]; }
        ss[0] = a; ssq[0] = c;
    }
    __syncthreads();
    float mean = ss[0] * (1.0f / D_MODEL);
    float var  = ssq[0] * (1.0f / D_MODEL) - mean * mean;
    float rstd = rsqrtf(var + 1e-5f);
    float4 gg = ((const float4*)g)[tid];
    float4 bb = ((const float4*)b)[tid];
    float4 o;
    o.x = (v.x - mean) * rstd * gg.x + bb.x;
    o.y = (v.y - mean) * rstd * gg.y + bb.y;
    o.z = (v.z - mean) * rstd * gg.z + bb.z;
    o.w = (v.w - mean) * rstd * gg.w + bb.w;
    ((float4*)outr)[tid] = o;
}

// ---------------- generic GEMM: C = act(A @ W^T [+bias]) [+res] ----------------
// A: [M,K] row-major with leading dim lda; W: [N,K] row-major (ld=K).
// 64x64 tile, 256 threads, 4x4 per thread, BK=16.
// ACT: 0=none, 1=softplus, 2=gelu
template<int ACT, bool BIAS, bool RES>
__global__ void gemm_kernel(const float* __restrict__ A, int lda,
                            const float* __restrict__ W,
                            const float* __restrict__ bias,
                            const float* __restrict__ res, int ldr,
                            float* __restrict__ C, int ldc,
                            int M, int N, int K) {
    const int BM = 64, BN = 64, BK = 16;
    __shared__ float As[BK][BM + 4];
    __shared__ float Ws[BK][BN + 4];
    int tid = threadIdx.x;
    int tx = tid & 15, ty = tid >> 4;
    int row0 = blockIdx.y * BM;
    int col0 = blockIdx.x * BN;
    float acc[4][4] = {};
    int lr = tid >> 2;        // 0..63: row within tile
    int lk = (tid & 3) * 4;   // 0,4,8,12: k offset (float4)

    for (int k0 = 0; k0 < K; k0 += BK) {
        {
            int gr = row0 + lr;
            float4 v = {0.f,0.f,0.f,0.f};
            if (gr < M) v = *(const float4*)(A + (size_t)gr * lda + k0 + lk);
            As[lk+0][lr] = v.x; As[lk+1][lr] = v.y; As[lk+2][lr] = v.z; As[lk+3][lr] = v.w;
        }
        {
            int gn = col0 + lr;
            float4 v = {0.f,0.f,0.f,0.f};
            if (gn < N) v = *(const float4*)(W + (size_t)gn * K + k0 + lk);
            Ws[lk+0][lr] = v.x; Ws[lk+1][lr] = v.y; Ws[lk+2][lr] = v.z; Ws[lk+3][lr] = v.w;
        }
        __syncthreads();
        #pragma unroll
        for (int k = 0; k < BK; k++) {
            float a[4], w[4];
            #pragma unroll
            for (int i = 0; i < 4; i++) a[i] = As[k][ty*4 + i];
            #pragma unroll
            for (int j = 0; j < 4; j++) w[j] = Ws[k][tx*4 + j];
            #pragma unroll
            for (int i = 0; i < 4; i++)
                #pragma unroll
                for (int j = 0; j < 4; j++)
                    acc[i][j] += a[i] * w[j];
        }
        __syncthreads();
    }

    #pragma unroll
    for (int i = 0; i < 4; i++) {
        int r = row0 + ty*4 + i;
        if (r >= M) continue;
        #pragma unroll
        for (int j = 0; j < 4; j++) {
            int c = col0 + tx*4 + j;
            if (c >= N) continue;
            float v = acc[i][j];
            if (BIAS) v += bias[c];
            if (ACT == 1) v = softplus_f(v);
            else if (ACT == 2) v = gelu_f(v);
            if (RES) v += res[(size_t)r * ldr + c];
            C[(size_t)r * ldc + c] = v;
        }
    }
}

// ---------------- causal depthwise conv (k=4) + silu ----------------
// input: xc part of xz [TOK,4096] (cols 0..2047); output xc [TOK,2048]
__global__ void conv_silu_kernel(const float* __restrict__ xz, const float* __restrict__ cw,
                                 const float* __restrict__ cb, float* __restrict__ xc) {
    int idx = blockIdx.x * 256 + threadIdx.x;      // TOK*D_INNER
    int c  = idx & (D_INNER - 1);
    int bt = idx >> 11;
    int b  = bt >> 10;
    int t  = bt & (SEQ - 1);
    float acc = cb[c];
    #pragma unroll
    for (int j = 0; j < 4; j++) {
        int tt = t - 3 + j;
        if (tt >= 0) acc += cw[c*4 + j] * xz[((size_t)(b*SEQ + tt)) * 4096 + c];
    }
    xc[idx] = silu_f(acc);
}

// ---------------- selective scan: one thread per (b, d) channel ----------------
__global__ void scan_kernel(const float* __restrict__ dt, const float* __restrict__ dbc,
                            const float* __restrict__ xc, const float* __restrict__ A_log,
                            float* __restrict__ y) {
    int idx = blockIdx.x * 256 + threadIdx.x;   // B*D_INNER = 4096
    int d = idx & (D_INNER - 1);
    int b = idx >> 11;
    float Arow[D_STATE];
    #pragma unroll
    for (int n = 0; n < D_STATE; n++) Arow[n] = -expf(A_log[d*D_STATE + n]);
    float h[D_STATE] = {};
    const size_t base = (size_t)b * SEQ;
    for (int t = 0; t < SEQ; t++) {
        size_t row = base + t;
        float dtv = dt[row * D_INNER + d];
        float xv  = xc[row * D_INNER + d];
        const float* bc = dbc + row * NBC;
        float dtx = dtv * xv;
        float yv = 0.f;
        #pragma unroll
        for (int n = 0; n < D_STATE; n++) {
            float dA = expf(dtv * Arow[n]);
            h[n] = dA * h[n] + dtx * bc[DT_RANK + n];
            yv += h[n] * bc[DT_RANK + D_STATE + n];
        }
        y[row * D_INNER + d] = yv;
    }
}

// ---------------- gating: y = (y + xc*D) * silu(z) ----------------
__global__ void gate_kernel(const float* __restrict__ y_in, const float* __restrict__ xc,
                            const float* __restrict__ xz, const float* __restrict__ Dp,
                            float* __restrict__ y_out) {
    int idx = blockIdx.x * 256 + threadIdx.x;   // TOK*D_INNER
    int c   = idx & (D_INNER - 1);
    int row = idx >> 11;
    float z = xz[(size_t)row * 4096 + 2048 + c];
    y_out[idx] = (y_in[idx] + xc[idx] * Dp[c]) * silu_f(z);
}

// ---------------- launch ----------------
extern "C" void kernel_launch(void* const* d_in, const int* in_sizes, int n_in,
                              void* d_out, int out_size, void* d_ws, size_t ws_size,
                              hipStream_t stream) {
    const float* x    = (const float*)d_in[0];
    const float* n1g  = (const float*)d_in[1];
    const float* n1b  = (const float*)d_in[2];
    const float* Wp   = (const float*)d_in[3];   // (4096,1024)
    const float* cw   = (const float*)d_in[4];   // (2048,1,4)
    const float* cb   = (const float*)d_in[5];
    const float* Wx   = (const float*)d_in[6];   // (96,2048)
    const float* Wdt  = (const float*)d_in[7];   // (2048,64)
    const float* bdt  = (const float*)d_in[8];
    const float* Alog = (const float*)d_in[9];   // (2048,16)
    const float* Dp   = (const float*)d_in[10];
    const float* Wo   = (const float*)d_in[11];  // (1024,2048)
    const float* n2g  = (const float*)d_in[12];
    const float* n2b  = (const float*)d_in[13];
    const float* W1   = (const float*)d_in[14];  // (2048,1024)
    const float* b1   = (const float*)d_in[15];
    const float* W2   = (const float*)d_in[16];  // (1024,2048)
    const float* b2   = (const float*)d_in[17];
    float* out = (float*)d_out;
    float* ws  = (float*)d_ws;

    const size_t M1 = 1024 * 1024;
    float* xn  = ws;            // 2M floats (reused as m)
    float* xz  = ws + 2*M1;     // 8M (reused as t1)
    float* xc  = ws + 10*M1;    // 4M
    float* dbc = ws + 14*M1;    // <1M
    float* dt  = ws + 15*M1;    // 4M (reused as h)
    float* y   = ws + 19*M1;    // 4M

    // 1. LN1
    ln_kernel<<<TOK, 256, 0, stream>>>(x, n1g, n1b, xn);
    // 2. in_proj: xz = xn @ Wp^T   (2048 x 4096 x 1024)
    gemm_kernel<0,false,false><<<dim3(4096/64, TOK/64), 256, 0, stream>>>(
        xn, D_MODEL, Wp, nullptr, nullptr, 0, xz, 2*D_INNER, TOK, 2*D_INNER, D_MODEL);
    // 3. conv + silu
    conv_silu_kernel<<<TOK*D_INNER/256, 256, 0, stream>>>(xz, cw, cb, xc);
    // 4. x_proj: dbc = xc @ Wx^T   (2048 x 96 x 2048)
    gemm_kernel<0,false,false><<<dim3((NBC+63)/64, TOK/64), 256, 0, stream>>>(
        xc, D_INNER, Wx, nullptr, nullptr, 0, dbc, NBC, TOK, NBC, D_INNER);
    // 5. dt = softplus(dbc[:, :64] @ Wdt^T + bdt)   (2048 x 2048 x 64)
    gemm_kernel<1,true,false><<<dim3(D_INNER/64, TOK/64), 256, 0, stream>>>(
        dbc, NBC, Wdt, bdt, nullptr, 0, dt, D_INNER, TOK, D_INNER, DT_RANK);
    // 6. selective scan
    scan_kernel<<<BATCH*D_INNER/256, 256, 0, stream>>>(dt, dbc, xc, Alog, y);
    // 7. gate: y = (y + xc*D) * silu(z)
    gate_kernel<<<TOK*D_INNER/256, 256, 0, stream>>>(y, xc, xz, Dp, y);
    // 8. out_proj + residual: h = x + y @ Wo^T   (2048 x 1024 x 2048) -> reuse dt buf
    float* hbuf = dt;
    gemm_kernel<0,false,true><<<dim3(D_MODEL/64, TOK/64), 256, 0, stream>>>(
        y, D_INNER, Wo, nullptr, x, D_MODEL, hbuf, D_MODEL, TOK, D_MODEL, D_INNER);
    // 9. LN2: m = LN(h) -> reuse xn
    float* m = xn;
    ln_kernel<<<TOK, 256, 0, stream>>>(hbuf, n2g, n2b, m);
    // 10. mlp1: t1 = gelu(m @ W1^T + b1)   (2048 x 2048 x 1024) -> reuse xz
    float* t1 = xz;
    gemm_kernel<2,true,false><<<dim3(D_INNER/64, TOK/64), 256, 0, stream>>>(
        m, D_MODEL, W1, b1, nullptr, 0, t1, D_INNER, TOK, D_INNER, D_MODEL);
    // 11. mlp2 + bias + residual: out = h + t1 @ W2^T + b2   (2048 x 1024 x 2048)
    gemm_kernel<0,true,true><<<dim3(D_MODEL/64, TOK/64), 256, 0, stream>>>(
        t1, D_INNER, W2, b2, hbuf, D_MODEL, out, D_MODEL, TOK, D_MODEL, D_INNER);
}

// Round 2
// 926.143 us; speedup vs baseline: 1.8513x; 1.8513x over previous
//
#include <hip/hip_runtime.h>
#include <math.h>

#define D_MODEL 1024
#define D_INNER 2048
#define DT_RANK 64
#define D_STATE 16
#define NBC 96   // DT_RANK + 2*D_STATE
#define BATCH 2
#define SEQ 1024
#define TOK (BATCH*SEQ)  // 2048
#define CS 32            // scan chunk size
#define NCH 32           // chunks per sequence (CS*NCH == SEQ)

// ---------------- device helpers ----------------
__device__ __forceinline__ float softplus_f(float x) {
    return (x > 20.0f) ? x : log1pf(expf(x));
}
__device__ __forceinline__ float gelu_f(float x) {
    return 0.5f * x * (1.0f + erff(x * 0.70710678118654752f));
}
__device__ __forceinline__ float silu_f(float x) {
    return x / (1.0f + expf(-x));
}

// ---------------- LayerNorm: one block per row (D=1024, 256 thr, float4) ----------------
__global__ void ln_kernel(const float* __restrict__ x, const float* __restrict__ g,
                          const float* __restrict__ b, float* __restrict__ out) {
    int row = blockIdx.x;
    const float* xr = x + (size_t)row * D_MODEL;
    float* outr = out + (size_t)row * D_MODEL;
    int tid = threadIdx.x;
    float4 v = ((const float4*)xr)[tid];
    float s  = v.x + v.y + v.z + v.w;
    float sq = v.x*v.x + v.y*v.y + v.z*v.z + v.w*v.w;
    #pragma unroll
    for (int o = 32; o > 0; o >>= 1) {
        s  += __shfl_down(s,  o);
        sq += __shfl_down(sq, o);
    }
    __shared__ float ss[4], ssq[4];
    int wid = tid >> 6, lane = tid & 63;
    if (lane == 0) { ss[wid] = s; ssq[wid] = sq; }
    __syncthreads();
    if (tid == 0) {
        float a = 0.f, c = 0.f;
        for (int i = 0; i < 4; i++) { a += ss[i]; c += ssq[i]; }
        ss[0] = a; ssq[0] = c;
    }
    __syncthreads();
    float mean = ss[0] * (1.0f / D_MODEL);
    float var  = ssq[0] * (1.0f / D_MODEL) - mean * mean;
    float rstd = rsqrtf(var + 1e-5f);
    float4 gg = ((const float4*)g)[tid];
    float4 bb = ((const float4*)b)[tid];
    float4 o;
    o.x = (v.x - mean) * rstd * gg.x + bb.x;
    o.y = (v.y - mean) * rstd * gg.y + bb.y;
    o.z = (v.z - mean) * rstd * gg.z + bb.z;
    o.w = (v.w - mean) * rstd * gg.w + bb.w;
    ((float4*)outr)[tid] = o;
}

// ---------------- generic GEMM: C = act(A @ W^T [+bias]) [+res] ----------------
template<int ACT, bool BIAS, bool RES>
__global__ void gemm_kernel(const float* __restrict__ A, int lda,
                            const float* __restrict__ W,
                            const float* __restrict__ bias,
                            const float* __restrict__ res, int ldr,
                            float* __restrict__ C, int ldc,
                            int M, int N, int K) {
    const int BM = 64, BN = 64, BK = 16;
    __shared__ float As[BK][BM + 4];
    __shared__ float Ws[BK][BN + 4];
    int tid = threadIdx.x;
    int tx = tid & 15, ty = tid >> 4;
    int row0 = blockIdx.y * BM;
    int col0 = blockIdx.x * BN;
    float acc[4][4] = {};
    int lr = tid >> 2;        // 0..63: row within tile
    int lk = (tid & 3) * 4;   // 0,4,8,12: k offset (float4)

    for (int k0 = 0; k0 < K; k0 += BK) {
        {
            int gr = row0 + lr;
            float4 v = {0.f,0.f,0.f,0.f};
            if (gr < M) v = *(const float4*)(A + (size_t)gr * lda + k0 + lk);
            As[lk+0][lr] = v.x; As[lk+1][lr] = v.y; As[lk+2][lr] = v.z; As[lk+3][lr] = v.w;
        }
        {
            int gn = col0 + lr;
            float4 v = {0.f,0.f,0.f,0.f};
            if (gn < N) v = *(const float4*)(W + (size_t)gn * K + k0 + lk);
            Ws[lk+0][lr] = v.x; Ws[lk+1][lr] = v.y; Ws[lk+2][lr] = v.z; Ws[lk+3][lr] = v.w;
        }
        __syncthreads();
        #pragma unroll
        for (int k = 0; k < BK; k++) {
            float a[4], w[4];
            #pragma unroll
            for (int i = 0; i < 4; i++) a[i] = As[k][ty*4 + i];
            #pragma unroll
            for (int j = 0; j < 4; j++) w[j] = Ws[k][tx*4 + j];
            #pragma unroll
            for (int i = 0; i < 4; i++)
                #pragma unroll
                for (int j = 0; j < 4; j++)
                    acc[i][j] += a[i] * w[j];
        }
        __syncthreads();
    }

    #pragma unroll
    for (int i = 0; i < 4; i++) {
        int r = row0 + ty*4 + i;
        if (r >= M) continue;
        #pragma unroll
        for (int j = 0; j < 4; j++) {
            int c = col0 + tx*4 + j;
            if (c >= N) continue;
            float v = acc[i][j];
            if (BIAS) v += bias[c];
            if (ACT == 1) v = softplus_f(v);
            else if (ACT == 2) v = gelu_f(v);
            if (RES) v += res[(size_t)r * ldr + c];
            C[(size_t)r * ldc + c] = v;
        }
    }
}

// ---------------- causal depthwise conv (k=4) + silu ----------------
__global__ void conv_silu_kernel(const float* __restrict__ xz, const float* __restrict__ cw,
                                 const float* __restrict__ cb, float* __restrict__ xc) {
    int idx = blockIdx.x * 256 + threadIdx.x;      // TOK*D_INNER
    int c  = idx & (D_INNER - 1);
    int bt = idx >> 11;
    int b  = bt >> 10;
    int t  = bt & (SEQ - 1);
    float acc = cb[c];
    #pragma unroll
    for (int j = 0; j < 4; j++) {
        int tt = t - 3 + j;
        if (tt >= 0) acc += cw[c*4 + j] * xz[((size_t)(b*SEQ + tt)) * 4096 + c];
    }
    xc[idx] = silu_f(acc);
}

// ---------------- chunked selective scan ----------------
// K1: per (b, chunk, d): local scan from h=0 -> aProd[16], hLocal[16]
// layout for chunk buffers: [b][c][n][d]  (d innermost, coalesced)
__global__ void scan_chunk_kernel(const float* __restrict__ dt, const float* __restrict__ dbc,
                                  const float* __restrict__ xc, const float* __restrict__ A_log,
                                  float* __restrict__ chunkA, float* __restrict__ chunkH) {
    int idx = blockIdx.x * 256 + threadIdx.x;   // B*NCH*D_INNER
    int d = idx & (D_INNER - 1);
    int r = idx >> 11;
    int c = r & (NCH - 1);
    int b = r >> 5;
    float Arow[D_STATE];
    #pragma unroll
    for (int n = 0; n < D_STATE; n++) Arow[n] = -expf(A_log[d*D_STATE + n]);
    float h[D_STATE] = {};
    float ap[D_STATE];
    #pragma unroll
    for (int n = 0; n < D_STATE; n++) ap[n] = 1.f;
    const size_t rbase = (size_t)(b * SEQ + c * CS);
    for (int t = 0; t < CS; t++) {
        size_t row = rbase + t;
        float dtv = dt[row * D_INNER + d];
        float xv  = xc[row * D_INNER + d];
        const float* bc = dbc + row * NBC + DT_RANK;
        float dtx = dtv * xv;
        #pragma unroll
        for (int n = 0; n < D_STATE; n++) {
            float dA = expf(dtv * Arow[n]);
            ap[n] *= dA;
            h[n] = dA * h[n] + dtx * bc[n];
        }
    }
    size_t obase = ((size_t)(b * NCH + c) * D_STATE) * D_INNER + d;
    #pragma unroll
    for (int n = 0; n < D_STATE; n++) {
        chunkA[obase + (size_t)n * D_INNER] = ap[n];
        chunkH[obase + (size_t)n * D_INNER] = h[n];
    }
}

// K2: per (b, n, d): compose chunk summaries serially; overwrite chunkH with
// the INCOMING state hIn for each chunk.
__global__ void scan_combine_kernel(const float* __restrict__ chunkA, float* __restrict__ chunkH) {
    int idx = blockIdx.x * 256 + threadIdx.x;   // B*D_STATE*D_INNER = 65536
    int d = idx & (D_INNER - 1);
    int r = idx >> 11;
    int n = r & (D_STATE - 1);
    int b = r >> 4;
    float h = 0.f;
    for (int c = 0; c < NCH; c++) {
        size_t o = ((size_t)((b * NCH + c) * D_STATE + n)) * D_INNER + d;
        float a  = chunkA[o];
        float hl = chunkH[o];
        chunkH[o] = h;          // hIn for chunk c
        h = a * h + hl;
    }
}

// K3: per (b, chunk, d): re-run chunk seeded with hIn, emit y
__global__ void scan_final_kernel(const float* __restrict__ dt, const float* __restrict__ dbc,
                                  const float* __restrict__ xc, const float* __restrict__ A_log,
                                  const float* __restrict__ chunkH, float* __restrict__ y) {
    int idx = blockIdx.x * 256 + threadIdx.x;   // B*NCH*D_INNER
    int d = idx & (D_INNER - 1);
    int r = idx >> 11;
    int c = r & (NCH - 1);
    int b = r >> 5;
    float Arow[D_STATE];
    #pragma unroll
    for (int n = 0; n < D_STATE; n++) Arow[n] = -expf(A_log[d*D_STATE + n]);
    float h[D_STATE];
    size_t obase = ((size_t)(b * NCH + c) * D_STATE) * D_INNER + d;
    #pragma unroll
    for (int n = 0; n < D_STATE; n++) h[n] = chunkH[obase + (size_t)n * D_INNER];
    const size_t rbase = (size_t)(b * SEQ + c * CS);
    for (int t = 0; t < CS; t++) {
        size_t row = rbase + t;
        float dtv = dt[row * D_INNER + d];
        float xv  = xc[row * D_INNER + d];
        const float* bc = dbc + row * NBC + DT_RANK;
        float dtx = dtv * xv;
        float yv = 0.f;
        #pragma unroll
        for (int n = 0; n < D_STATE; n++) {
            float dA = expf(dtv * Arow[n]);
            h[n] = dA * h[n] + dtx * bc[n];
            yv += h[n] * bc[D_STATE + n];
        }
        y[row * D_INNER + d] = yv;
    }
}

// ---------------- gating: y = (y + xc*D) * silu(z) ----------------
__global__ void gate_kernel(const float* __restrict__ y_in, const float* __restrict__ xc,
                            const float* __restrict__ xz, const float* __restrict__ Dp,
                            float* __restrict__ y_out) {
    int idx = blockIdx.x * 256 + threadIdx.x;   // TOK*D_INNER
    int c   = idx & (D_INNER - 1);
    int row = idx >> 11;
    float z = xz[(size_t)row * 4096 + 2048 + c];
    y_out[idx] = (y_in[idx] + xc[idx] * Dp[c]) * silu_f(z);
}

// ---------------- launch ----------------
extern "C" void kernel_launch(void* const* d_in, const int* in_sizes, int n_in,
                              void* d_out, int out_size, void* d_ws, size_t ws_size,
                              hipStream_t stream) {
    const float* x    = (const float*)d_in[0];
    const float* n1g  = (const float*)d_in[1];
    const float* n1b  = (const float*)d_in[2];
    const float* Wp   = (const float*)d_in[3];   // (4096,1024)
    const float* cw   = (const float*)d_in[4];   // (2048,1,4)
    const float* cb   = (const float*)d_in[5];
    const float* Wx   = (const float*)d_in[6];   // (96,2048)
    const float* Wdt  = (const float*)d_in[7];   // (2048,64)
    const float* bdt  = (const float*)d_in[8];
    const float* Alog = (const float*)d_in[9];   // (2048,16)
    const float* Dp   = (const float*)d_in[10];
    const float* Wo   = (const float*)d_in[11];  // (1024,2048)
    const float* n2g  = (const float*)d_in[12];
    const float* n2b  = (const float*)d_in[13];
    const float* W1   = (const float*)d_in[14];  // (2048,1024)
    const float* b1   = (const float*)d_in[15];
    const float* W2   = (const float*)d_in[16];  // (1024,2048)
    const float* b2   = (const float*)d_in[17];
    float* out = (float*)d_out;
    float* ws  = (float*)d_ws;

    const size_t M1 = 1024 * 1024;
    float* xn  = ws;            // 2M floats (reused: chunkA during scan, m after)
    float* xz  = ws + 2*M1;     // 8M (reused as t1)
    float* xc  = ws + 10*M1;    // 4M
    float* dbc = ws + 14*M1;    // <1M
    float* dt  = ws + 15*M1;    // 4M (reused as h)
    float* y   = ws + 19*M1;    // 4M

    // scan scratch: chunkA in xn region (B*NCH*16*D = 2M floats exactly),
    // chunkH in d_out (2M floats; fully overwritten by step 11)
    float* chunkA = xn;
    float* chunkH = out;

    // 1. LN1
    ln_kernel<<<TOK, 256, 0, stream>>>(x, n1g, n1b, xn);
    // 2. in_proj: xz = xn @ Wp^T   (2048 x 4096 x 1024)
    gemm_kernel<0,false,false><<<dim3(4096/64, TOK/64), 256, 0, stream>>>(
        xn, D_MODEL, Wp, nullptr, nullptr, 0, xz, 2*D_INNER, TOK, 2*D_INNER, D_MODEL);
    // 3. conv + silu
    conv_silu_kernel<<<TOK*D_INNER/256, 256, 0, stream>>>(xz, cw, cb, xc);
    // 4. x_proj: dbc = xc @ Wx^T   (2048 x 96 x 2048)
    gemm_kernel<0,false,false><<<dim3((NBC+63)/64, TOK/64), 256, 0, stream>>>(
        xc, D_INNER, Wx, nullptr, nullptr, 0, dbc, NBC, TOK, NBC, D_INNER);
    // 5. dt = softplus(dbc[:, :64] @ Wdt^T + bdt)   (2048 x 2048 x 64)
    gemm_kernel<1,true,false><<<dim3(D_INNER/64, TOK/64), 256, 0, stream>>>(
        dbc, NBC, Wdt, bdt, nullptr, 0, dt, D_INNER, TOK, D_INNER, DT_RANK);
    // 6. chunked selective scan (K1: local, K2: combine, K3: final+y)
    scan_chunk_kernel<<<BATCH*NCH*D_INNER/256, 256, 0, stream>>>(dt, dbc, xc, Alog, chunkA, chunkH);
    scan_combine_kernel<<<BATCH*D_STATE*D_INNER/256, 256, 0, stream>>>(chunkA, chunkH);
    scan_final_kernel<<<BATCH*NCH*D_INNER/256, 256, 0, stream>>>(dt, dbc, xc, Alog, chunkH, y);
    // 7. gate: y = (y + xc*D) * silu(z)
    gate_kernel<<<TOK*D_INNER/256, 256, 0, stream>>>(y, xc, xz, Dp, y);
    // 8. out_proj + residual: h = x + y @ Wo^T -> reuse dt buf
    float* hbuf = dt;
    gemm_kernel<0,false,true><<<dim3(D_MODEL/64, TOK/64), 256, 0, stream>>>(
        y, D_INNER, Wo, nullptr, x, D_MODEL, hbuf, D_MODEL, TOK, D_MODEL, D_INNER);
    // 9. LN2: m = LN(h) -> reuse xn
    float* m = xn;
    ln_kernel<<<TOK, 256, 0, stream>>>(hbuf, n2g, n2b, m);
    // 10. mlp1: t1 = gelu(m @ W1^T + b1) -> reuse xz
    float* t1 = xz;
    gemm_kernel<2,true,false><<<dim3(D_INNER/64, TOK/64), 256, 0, stream>>>(
        m, D_MODEL, W1, b1, nullptr, 0, t1, D_INNER, TOK, D_INNER, D_MODEL);
    // 11. mlp2 + bias + residual: out = h + t1 @ W2^T + b2
    gemm_kernel<0,true,true><<<dim3(D_MODEL/64, TOK/64), 256, 0, stream>>>(
        t1, D_INNER, W2, b2, hbuf, D_MODEL, out, D_MODEL, TOK, D_MODEL, D_INNER);
}

// Round 3
// 436.059 us; speedup vs baseline: 3.9319x; 2.1239x over previous
//
#include <hip/hip_runtime.h>
#include <math.h>

#define D_MODEL 1024
#define D_INNER 2048
#define DT_RANK 64
#define D_STATE 16
#define NBC 96   // DT_RANK + 2*D_STATE
#define BATCH 2
#define SEQ 1024
#define TOK (BATCH*SEQ)  // 2048
#define CS 32            // scan chunk size
#define NCH 32           // chunks per sequence

typedef __attribute__((ext_vector_type(8))) short short8;
typedef __attribute__((ext_vector_type(4))) float f32x4;

// ---------------- device helpers ----------------
__device__ __forceinline__ float softplus_f(float x) {
    return (x > 20.0f) ? x : log1pf(expf(x));
}
__device__ __forceinline__ float gelu_f(float x) {
    return 0.5f * x * (1.0f + erff(x * 0.70710678118654752f));
}
__device__ __forceinline__ float silu_f(float x) {
    return x / (1.0f + expf(-x));
}
__device__ __forceinline__ ushort f2bf(float f) {   // fp32 -> bf16 RNE
    unsigned u = __float_as_uint(f);
    unsigned r = (u + 0x7fffu + ((u >> 16) & 1u)) >> 16;
    return (ushort)r;
}

// ---------------- fp32 -> bf16 convert (float4 -> ushort4) ----------------
__global__ void f2bf4_kernel(const float* __restrict__ in, ushort* __restrict__ out, int n4) {
    int i = blockIdx.x * 256 + threadIdx.x;
    if (i >= n4) return;
    float4 v = ((const float4*)in)[i];
    ushort4 o;
    o.x = f2bf(v.x); o.y = f2bf(v.y); o.z = f2bf(v.z); o.w = f2bf(v.w);
    ((ushort4*)out)[i] = o;
}

// ---------------- LayerNorm -> bf16 out: one block per row ----------------
__global__ void ln_bf16_kernel(const float* __restrict__ x, const float* __restrict__ g,
                               const float* __restrict__ b, ushort* __restrict__ out) {
    int row = blockIdx.x;
    const float* xr = x + (size_t)row * D_MODEL;
    ushort* outr = out + (size_t)row * D_MODEL;
    int tid = threadIdx.x;
    float4 v = ((const float4*)xr)[tid];
    float s  = v.x + v.y + v.z + v.w;
    float sq = v.x*v.x + v.y*v.y + v.z*v.z + v.w*v.w;
    #pragma unroll
    for (int o = 32; o > 0; o >>= 1) {
        s  += __shfl_down(s,  o);
        sq += __shfl_down(sq, o);
    }
    __shared__ float ss[4], ssq[4];
    int wid = tid >> 6, lane = tid & 63;
    if (lane == 0) { ss[wid] = s; ssq[wid] = sq; }
    __syncthreads();
    if (tid == 0) {
        float a = 0.f, c = 0.f;
        for (int i = 0; i < 4; i++) { a += ss[i]; c += ssq[i]; }
        ss[0] = a; ssq[0] = c;
    }
    __syncthreads();
    float mean = ss[0] * (1.0f / D_MODEL);
    float var  = ssq[0] * (1.0f / D_MODEL) - mean * mean;
    float rstd = rsqrtf(var + 1e-5f);
    float4 gg = ((const float4*)g)[tid];
    float4 bb = ((const float4*)b)[tid];
    ushort4 o;
    o.x = f2bf((v.x - mean) * rstd * gg.x + bb.x);
    o.y = f2bf((v.y - mean) * rstd * gg.y + bb.y);
    o.z = f2bf((v.z - mean) * rstd * gg.z + bb.z);
    o.w = f2bf((v.w - mean) * rstd * gg.w + bb.w);
    ((ushort4*)outr)[tid] = o;
}

// ---------------- bf16 MFMA GEMM: C = act(A @ W^T [+bias]) [+res] ----------------
// A: [M,K] bf16 row-major; W: [N,K] bf16 row-major. M,N multiples of BM/BN, K of 32.
// 256 threads = 4 waves in 2x2; wave computes (BM/2)x(BN/2).
// m97 structure: global_load_lds(16B) staging, linear LDS, 2-barrier K-loop.
template<int BM, int BN, int ACT, bool BIAS, bool RES, bool OUTBF>
__global__ __launch_bounds__(256)
void mfma_gemm(const ushort* __restrict__ A, const ushort* __restrict__ W,
               const float* __restrict__ bias,
               const float* __restrict__ res, int ldr,
               void* __restrict__ Cout, int ldc, int K) {
    constexpr int WM = BM / 2, WN = BN / 2, FM = WM / 16, FN = WN / 16;
    __shared__ __align__(16) ushort As[BM * 32];
    __shared__ __align__(16) ushort Ws[BN * 32];
    const int tid  = threadIdx.x;
    const int lane = tid & 63, w = tid >> 6;
    const int wr = w >> 1, wc = w & 1;
    const int row0 = blockIdx.y * BM, col0 = blockIdx.x * BN;
    const int l16 = lane >> 4, l15 = lane & 15;
    const int srow = tid >> 2;           // staging row within 64-row shot
    const int scol = (tid & 3) * 8;      // staging col (elements)

    f32x4 acc[FM][FN] = {};

    for (int k0 = 0; k0 < K; k0 += 32) {
        #pragma unroll
        for (int s = 0; s < BM / 64; s++) {
            const ushort* g = A + (size_t)(row0 + s * 64 + srow) * K + k0 + scol;
            __builtin_amdgcn_global_load_lds(
                (const __attribute__((address_space(1))) void*)g,
                (__attribute__((address_space(3))) void*)((char*)As + s * 4096 + w * 1024),
                16, 0, 0);
        }
        #pragma unroll
        for (int s = 0; s < BN / 64; s++) {
            const ushort* g = W + (size_t)(col0 + s * 64 + srow) * K + k0 + scol;
            __builtin_amdgcn_global_load_lds(
                (const __attribute__((address_space(1))) void*)g,
                (__attribute__((address_space(3))) void*)((char*)Ws + s * 4096 + w * 1024),
                16, 0, 0);
        }
        __syncthreads();   // drains vmcnt before barrier (compiler-inserted)

        short8 a[FM], b[FN];
        #pragma unroll
        for (int m = 0; m < FM; m++)
            a[m] = *(const short8*)(As + (wr * WM + m * 16 + l15) * 32 + l16 * 8);
        #pragma unroll
        for (int n = 0; n < FN; n++)
            b[n] = *(const short8*)(Ws + (wc * WN + n * 16 + l15) * 32 + l16 * 8);
        #pragma unroll
        for (int m = 0; m < FM; m++)
            #pragma unroll
            for (int n = 0; n < FN; n++)
                acc[m][n] = __builtin_amdgcn_mfma_f32_16x16x32_bf16(a[m], b[n], acc[m][n], 0, 0, 0);
        __syncthreads();
    }

    // epilogue: C/D layout col=lane&15, row=(lane>>4)*4+reg  [m89-verified]
    #pragma unroll
    for (int m = 0; m < FM; m++) {
        const int r0 = row0 + wr * WM + m * 16 + l16 * 4;
        #pragma unroll
        for (int n = 0; n < FN; n++) {
            const int c = col0 + wc * WN + n * 16 + l15;
            const float bv = BIAS ? bias[c] : 0.f;
            #pragma unroll
            for (int q = 0; q < 4; q++) {
                const int r = r0 + q;
                float v = acc[m][n][q] + bv;
                if (ACT == 2) v = gelu_f(v);
                if (RES) v += res[(size_t)r * ldr + c];
                if (OUTBF) ((ushort*)Cout)[(size_t)r * ldc + c] = f2bf(v);
                else       ((float*)Cout)[(size_t)r * ldc + c] = v;
            }
        }
    }
}

// ---------------- fp32 vector GEMM (kept for x_proj / dt_proj) ----------------
template<int ACT, bool BIAS, bool RES>
__global__ void gemm_kernel(const float* __restrict__ A, int lda,
                            const float* __restrict__ W,
                            const float* __restrict__ bias,
                            const float* __restrict__ res, int ldr,
                            float* __restrict__ C, int ldc,
                            int M, int N, int K) {
    const int BM = 64, BN = 64, BK = 16;
    __shared__ float As[BK][BM + 4];
    __shared__ float Ws[BK][BN + 4];
    int tid = threadIdx.x;
    int tx = tid & 15, ty = tid >> 4;
    int row0 = blockIdx.y * BM;
    int col0 = blockIdx.x * BN;
    float acc[4][4] = {};
    int lr = tid >> 2;
    int lk = (tid & 3) * 4;

    for (int k0 = 0; k0 < K; k0 += BK) {
        {
            int gr = row0 + lr;
            float4 v = {0.f,0.f,0.f,0.f};
            if (gr < M) v = *(const float4*)(A + (size_t)gr * lda + k0 + lk);
            As[lk+0][lr] = v.x; As[lk+1][lr] = v.y; As[lk+2][lr] = v.z; As[lk+3][lr] = v.w;
        }
        {
            int gn = col0 + lr;
            float4 v = {0.f,0.f,0.f,0.f};
            if (gn < N) v = *(const float4*)(W + (size_t)gn * K + k0 + lk);
            Ws[lk+0][lr] = v.x; Ws[lk+1][lr] = v.y; Ws[lk+2][lr] = v.z; Ws[lk+3][lr] = v.w;
        }
        __syncthreads();
        #pragma unroll
        for (int k = 0; k < BK; k++) {
            float a[4], wv[4];
            #pragma unroll
            for (int i = 0; i < 4; i++) a[i] = As[k][ty*4 + i];
            #pragma unroll
            for (int j = 0; j < 4; j++) wv[j] = Ws[k][tx*4 + j];
            #pragma unroll
            for (int i = 0; i < 4; i++)
                #pragma unroll
                for (int j = 0; j < 4; j++)
                    acc[i][j] += a[i] * wv[j];
        }
        __syncthreads();
    }

    #pragma unroll
    for (int i = 0; i < 4; i++) {
        int r = row0 + ty*4 + i;
        if (r >= M) continue;
        #pragma unroll
        for (int j = 0; j < 4; j++) {
            int c = col0 + tx*4 + j;
            if (c >= N) continue;
            float v = acc[i][j];
            if (BIAS) v += bias[c];
            if (ACT == 1) v = softplus_f(v);
            if (RES) v += res[(size_t)r * ldr + c];
            C[(size_t)r * ldc + c] = v;
        }
    }
}

// ---------------- causal depthwise conv (k=4) + silu ----------------
__global__ void conv_silu_kernel(const float* __restrict__ xz, const float* __restrict__ cw,
                                 const float* __restrict__ cb, float* __restrict__ xc) {
    int idx = blockIdx.x * 256 + threadIdx.x;      // TOK*D_INNER
    int c  = idx & (D_INNER - 1);
    int bt = idx >> 11;
    int b  = bt >> 10;
    int t  = bt & (SEQ - 1);
    float acc = cb[c];
    #pragma unroll
    for (int j = 0; j < 4; j++) {
        int tt = t - 3 + j;
        if (tt >= 0) acc += cw[c*4 + j] * xz[((size_t)(b*SEQ + tt)) * 4096 + c];
    }
    xc[idx] = silu_f(acc);
}

// ---------------- chunked selective scan ----------------
__global__ void scan_chunk_kernel(const float* __restrict__ dt, const float* __restrict__ dbc,
                                  const float* __restrict__ xc, const float* __restrict__ A_log,
                                  float* __restrict__ chunkA, float* __restrict__ chunkH) {
    int idx = blockIdx.x * 256 + threadIdx.x;   // B*NCH*D_INNER
    int d = idx & (D_INNER - 1);
    int r = idx >> 11;
    int c = r & (NCH - 1);
    int b = r >> 5;
    float Arow[D_STATE];
    #pragma unroll
    for (int n = 0; n < D_STATE; n++) Arow[n] = -expf(A_log[d*D_STATE + n]);
    float h[D_STATE] = {};
    float ap[D_STATE];
    #pragma unroll
    for (int n = 0; n < D_STATE; n++) ap[n] = 1.f;
    const size_t rbase = (size_t)(b * SEQ + c * CS);
    for (int t = 0; t < CS; t++) {
        size_t row = rbase + t;
        float dtv = dt[row * D_INNER + d];
        float xv  = xc[row * D_INNER + d];
        const float* bc = dbc + row * NBC + DT_RANK;
        float dtx = dtv * xv;
        #pragma unroll
        for (int n = 0; n < D_STATE; n++) {
            float dA = expf(dtv * Arow[n]);
            ap[n] *= dA;
            h[n] = dA * h[n] + dtx * bc[n];
        }
    }
    size_t obase = ((size_t)(b * NCH + c) * D_STATE) * D_INNER + d;
    #pragma unroll
    for (int n = 0; n < D_STATE; n++) {
        chunkA[obase + (size_t)n * D_INNER] = ap[n];
        chunkH[obase + (size_t)n * D_INNER] = h[n];
    }
}

__global__ void scan_combine_kernel(const float* __restrict__ chunkA, float* __restrict__ chunkH) {
    int idx = blockIdx.x * 256 + threadIdx.x;   // B*D_STATE*D_INNER
    int d = idx & (D_INNER - 1);
    int r = idx >> 11;
    int n = r & (D_STATE - 1);
    int b = r >> 4;
    float h = 0.f;
    for (int c = 0; c < NCH; c++) {
        size_t o = ((size_t)((b * NCH + c) * D_STATE + n)) * D_INNER + d;
        float a  = chunkA[o];
        float hl = chunkH[o];
        chunkH[o] = h;
        h = a * h + hl;
    }
}

__global__ void scan_final_kernel(const float* __restrict__ dt, const float* __restrict__ dbc,
                                  const float* __restrict__ xc, const float* __restrict__ A_log,
                                  const float* __restrict__ chunkH, float* __restrict__ y) {
    int idx = blockIdx.x * 256 + threadIdx.x;   // B*NCH*D_INNER
    int d = idx & (D_INNER - 1);
    int r = idx >> 11;
    int c = r & (NCH - 1);
    int b = r >> 5;
    float Arow[D_STATE];
    #pragma unroll
    for (int n = 0; n < D_STATE; n++) Arow[n] = -expf(A_log[d*D_STATE + n]);
    float h[D_STATE];
    size_t obase = ((size_t)(b * NCH + c) * D_STATE) * D_INNER + d;
    #pragma unroll
    for (int n = 0; n < D_STATE; n++) h[n] = chunkH[obase + (size_t)n * D_INNER];
    const size_t rbase = (size_t)(b * SEQ + c * CS);
    for (int t = 0; t < CS; t++) {
        size_t row = rbase + t;
        float dtv = dt[row * D_INNER + d];
        float xv  = xc[row * D_INNER + d];
        const float* bc = dbc + row * NBC + DT_RANK;
        float dtx = dtv * xv;
        float yv = 0.f;
        #pragma unroll
        for (int n = 0; n < D_STATE; n++) {
            float dA = expf(dtv * Arow[n]);
            h[n] = dA * h[n] + dtx * bc[n];
            yv += h[n] * bc[D_STATE + n];
        }
        y[row * D_INNER + d] = yv;
    }
}

// ---------------- gating -> bf16: yb = (y + xc*D) * silu(z) ----------------
__global__ void gate_kernel(const float* __restrict__ y_in, const float* __restrict__ xc,
                            const float* __restrict__ xz, const float* __restrict__ Dp,
                            ushort* __restrict__ y_out) {
    int idx = blockIdx.x * 256 + threadIdx.x;   // TOK*D_INNER
    int c   = idx & (D_INNER - 1);
    int row = idx >> 11;
    float z = xz[(size_t)row * 4096 + 2048 + c];
    y_out[idx] = f2bf((y_in[idx] + xc[idx] * Dp[c]) * silu_f(z));
}

// ---------------- launch ----------------
extern "C" void kernel_launch(void* const* d_in, const int* in_sizes, int n_in,
                              void* d_out, int out_size, void* d_ws, size_t ws_size,
                              hipStream_t stream) {
    const float* x    = (const float*)d_in[0];
    const float* n1g  = (const float*)d_in[1];
    const float* n1b  = (const float*)d_in[2];
    const float* Wp   = (const float*)d_in[3];   // (4096,1024)
    const float* cw   = (const float*)d_in[4];   // (2048,1,4)
    const float* cb   = (const float*)d_in[5];
    const float* Wx   = (const float*)d_in[6];   // (96,2048)
    const float* Wdt  = (const float*)d_in[7];   // (2048,64)
    const float* bdt  = (const float*)d_in[8];
    const float* Alog = (const float*)d_in[9];   // (2048,16)
    const float* Dp   = (const float*)d_in[10];
    const float* Wo   = (const float*)d_in[11];  // (1024,2048)
    const float* n2g  = (const float*)d_in[12];
    const float* n2b  = (const float*)d_in[13];
    const float* W1   = (const float*)d_in[14];  // (2048,1024)
    const float* b1   = (const float*)d_in[15];
    const float* W2   = (const float*)d_in[16];  // (1024,2048)
    const float* b2   = (const float*)d_in[17];
    float* out = (float*)d_out;
    float* ws  = (float*)d_ws;

    const size_t M1 = 1024 * 1024;
    float*  xz   = ws;                         // 8M floats [TOK,4096]
    float*  xc   = ws + 8*M1;                  // 4M
    float*  dtb  = ws + 12*M1;                 // 4M
    float*  y    = ws + 16*M1;                 // 4M (hbuf reuses first 2M after gate)
    float*  hbuf = y;
    float*  dbc  = ws + 20*M1;                 // 1M
    ushort* xnb  = (ushort*)(ws + 21*M1);      // 2M bf16 (mb reuses)
    ushort* mb   = xnb;
    ushort* yb   = (ushort*)(ws + 22*M1);      // 4M bf16 (t1b reuses)
    ushort* t1b  = yb;
    ushort* Wpb  = (ushort*)(ws + 24*M1);      // 4M bf16 (chunkA reuses as fp32)
    float*  chunkA = ws + 24*M1;
    ushort* Wob  = (ushort*)(ws + 26*M1);      // 2M bf16
    ushort* W1b  = (ushort*)(ws + 27*M1);      // 2M bf16
    ushort* W2b  = (ushort*)(ws + 28*M1);      // 2M bf16  (total 29M floats = 116MB)
    float*  chunkH = out;                      // 2M fp32, overwritten by final GEMM

    // 0. weight fp32->bf16 (every call; deterministic)
    f2bf4_kernel<<<4096, 256, 0, stream>>>(Wp, Wpb, 4096*1024/4);
    f2bf4_kernel<<<2048, 256, 0, stream>>>(Wo, Wob, 1024*2048/4);
    f2bf4_kernel<<<2048, 256, 0, stream>>>(W1, W1b, 2048*1024/4);
    f2bf4_kernel<<<2048, 256, 0, stream>>>(W2, W2b, 1024*2048/4);

    // 1. LN1 -> bf16
    ln_bf16_kernel<<<TOK, 256, 0, stream>>>(x, n1g, n1b, xnb);
    // 2. in_proj (MFMA): xz = xnb @ Wpb^T   M=2048 N=4096 K=1024
    mfma_gemm<128,128,0,false,false,false><<<dim3(4096/128, 2048/128), 256, 0, stream>>>(
        xnb, Wpb, nullptr, nullptr, 0, xz, 2*D_INNER, D_MODEL);
    // 3. conv + silu
    conv_silu_kernel<<<TOK*D_INNER/256, 256, 0, stream>>>(xz, cw, cb, xc);
    // 4. x_proj (fp32): dbc = xc @ Wx^T
    gemm_kernel<0,false,false><<<dim3((NBC+63)/64, TOK/64), 256, 0, stream>>>(
        xc, D_INNER, Wx, nullptr, nullptr, 0, dbc, NBC, TOK, NBC, D_INNER);
    // 5. dt_proj (fp32): dt = softplus(dbc[:,:64] @ Wdt^T + bdt)
    gemm_kernel<1,true,false><<<dim3(D_INNER/64, TOK/64), 256, 0, stream>>>(
        dbc, NBC, Wdt, bdt, nullptr, 0, dtb, D_INNER, TOK, D_INNER, DT_RANK);
    // 6. chunked selective scan
    scan_chunk_kernel<<<BATCH*NCH*D_INNER/256, 256, 0, stream>>>(dtb, dbc, xc, Alog, chunkA, chunkH);
    scan_combine_kernel<<<BATCH*D_STATE*D_INNER/256, 256, 0, stream>>>(chunkA, chunkH);
    scan_final_kernel<<<BATCH*NCH*D_INNER/256, 256, 0, stream>>>(dtb, dbc, xc, Alog, chunkH, y);
    // 7. gate -> bf16
    gate_kernel<<<TOK*D_INNER/256, 256, 0, stream>>>(y, xc, xz, Dp, yb);
    // 8. out_proj (MFMA) + residual: hbuf = x + yb @ Wob^T   M=2048 N=1024 K=2048
    mfma_gemm<128,64,0,false,true,false><<<dim3(1024/64, 2048/128), 256, 0, stream>>>(
        yb, Wob, nullptr, x, D_MODEL, hbuf, D_MODEL, D_INNER);
    // 9. LN2 -> bf16
    ln_bf16_kernel<<<TOK, 256, 0, stream>>>(hbuf, n2g, n2b, mb);
    // 10. mlp1 (MFMA): t1b = bf16(gelu(mb @ W1b^T + b1))   M=2048 N=2048 K=1024
    mfma_gemm<128,128,2,true,false,true><<<dim3(2048/128, 2048/128), 256, 0, stream>>>(
        mb, W1b, b1, nullptr, 0, t1b, D_INNER, D_MODEL);
    // 11. mlp2 (MFMA) + bias + residual: out = hbuf + t1b @ W2b^T + b2
    mfma_gemm<128,64,0,true,true,false><<<dim3(1024/64, 2048/128), 256, 0, stream>>>(
        t1b, W2b, b2, hbuf, D_MODEL, out, D_MODEL, D_INNER);
}

// Round 5
// 319.003 us; speedup vs baseline: 5.3747x; 1.3669x over previous
//
#include <hip/hip_runtime.h>
#include <math.h>

#define D_MODEL 1024
#define D_INNER 2048
#define DT_RANK 64
#define D_STATE 16
#define NBC 96   // DT_RANK + 2*D_STATE
#define BATCH 2
#define SEQ 1024
#define TOK (BATCH*SEQ)  // 2048
#define CS 32            // scan chunk size
#define NCH 32           // chunks per sequence
#define XKSPLIT 16       // x_proj K-split

typedef __attribute__((ext_vector_type(8))) short short8;
typedef __attribute__((ext_vector_type(4))) float f32x4;

// ---------------- device helpers ----------------
__device__ __forceinline__ float softplus_f(float x) {
    return (x > 20.0f) ? x : log1pf(expf(x));
}
__device__ __forceinline__ float gelu_f(float x) {
    return 0.5f * x * (1.0f + erff(x * 0.70710678118654752f));
}
__device__ __forceinline__ float silu_f(float x) {
    return x / (1.0f + expf(-x));
}
__device__ __forceinline__ ushort f2bf(float f) {   // fp32 -> bf16 RNE
    unsigned u = __float_as_uint(f);
    unsigned r = (u + 0x7fffu + ((u >> 16) & 1u)) >> 16;
    return (ushort)r;
}
__device__ __forceinline__ float bf2f(ushort u) {
    return __uint_as_float(((unsigned)u) << 16);
}

// ---------------- fused weight fp32->bf16 convert (all 6 weights, 1 launch) ----------------
__global__ void convert_weights_kernel(const float* __restrict__ Wp, const float* __restrict__ Wo,
                                       const float* __restrict__ W1, const float* __restrict__ W2,
                                       const float* __restrict__ Wx, const float* __restrict__ Wdt,
                                       ushort* __restrict__ Wpb, ushort* __restrict__ Wob,
                                       ushort* __restrict__ W1b, ushort* __restrict__ W2b,
                                       ushort* __restrict__ Wxb, ushort* __restrict__ Wdtb) {
    int i = blockIdx.x * 256 + threadIdx.x;  // float4 index
    const float* src; ushort* dst; int off;
    if      (i < 1048576) { src = Wp;  dst = Wpb;  off = i; }
    else if (i < 1572864) { src = Wo;  dst = Wob;  off = i - 1048576; }
    else if (i < 2097152) { src = W1;  dst = W1b;  off = i - 1572864; }
    else if (i < 2621440) { src = W2;  dst = W2b;  off = i - 2097152; }
    else if (i < 2670592) { src = Wx;  dst = Wxb;  off = i - 2621440; }
    else if (i < 2703360) { src = Wdt; dst = Wdtb; off = i - 2670592; }
    else return;
    float4 v = ((const float4*)src)[off];
    ushort4 o;
    o.x = f2bf(v.x); o.y = f2bf(v.y); o.z = f2bf(v.z); o.w = f2bf(v.w);
    ((ushort4*)dst)[off] = o;
}

// ---------------- LayerNorm -> bf16 out ----------------
__global__ void ln_bf16_kernel(const float* __restrict__ x, const float* __restrict__ g,
                               const float* __restrict__ b, ushort* __restrict__ out) {
    int row = blockIdx.x;
    const float* xr = x + (size_t)row * D_MODEL;
    ushort* outr = out + (size_t)row * D_MODEL;
    int tid = threadIdx.x;
    float4 v = ((const float4*)xr)[tid];
    float s  = v.x + v.y + v.z + v.w;
    float sq = v.x*v.x + v.y*v.y + v.z*v.z + v.w*v.w;
    #pragma unroll
    for (int o = 32; o > 0; o >>= 1) {
        s  += __shfl_down(s,  o);
        sq += __shfl_down(sq, o);
    }
    __shared__ float ss[4], ssq[4];
    int wid = tid >> 6, lane = tid & 63;
    if (lane == 0) { ss[wid] = s; ssq[wid] = sq; }
    __syncthreads();
    if (tid == 0) {
        float a = 0.f, c = 0.f;
        for (int i = 0; i < 4; i++) { a += ss[i]; c += ssq[i]; }
        ss[0] = a; ssq[0] = c;
    }
    __syncthreads();
    float mean = ss[0] * (1.0f / D_MODEL);
    float var  = ssq[0] * (1.0f / D_MODEL) - mean * mean;
    float rstd = rsqrtf(var + 1e-5f);
    float4 gg = ((const float4*)g)[tid];
    float4 bb = ((const float4*)b)[tid];
    ushort4 o;
    o.x = f2bf((v.x - mean) * rstd * gg.x + bb.x);
    o.y = f2bf((v.y - mean) * rstd * gg.y + bb.y);
    o.z = f2bf((v.z - mean) * rstd * gg.z + bb.z);
    o.w = f2bf((v.w - mean) * rstd * gg.w + bb.w);
    ((ushort4*)outr)[tid] = o;
}

// ---------------- bf16 MFMA GEMM: C = act(A @ W^T [+bias]) [+res] ----------------
// ACT: 0=none, 1=softplus, 2=gelu
template<int BM, int BN, int ACT, bool BIAS, bool RES, bool OUTBF>
__global__ __launch_bounds__(256)
void mfma_gemm(const ushort* __restrict__ A, const ushort* __restrict__ W,
               const float* __restrict__ bias,
               const float* __restrict__ res, int ldr,
               void* __restrict__ Cout, int ldc, int K) {
    constexpr int WM = BM / 2, WN = BN / 2, FM = WM / 16, FN = WN / 16;
    __shared__ __align__(16) ushort As[BM * 32];
    __shared__ __align__(16) ushort Ws[BN * 32];
    const int tid  = threadIdx.x;
    const int lane = tid & 63, w = tid >> 6;
    const int wr = w >> 1, wc = w & 1;
    const int row0 = blockIdx.y * BM, col0 = blockIdx.x * BN;
    const int l16 = lane >> 4, l15 = lane & 15;
    const int srow = tid >> 2;
    const int scol = (tid & 3) * 8;

    f32x4 acc[FM][FN] = {};

    for (int k0 = 0; k0 < K; k0 += 32) {
        #pragma unroll
        for (int s = 0; s < BM / 64; s++) {
            const ushort* g = A + (size_t)(row0 + s * 64 + srow) * K + k0 + scol;
            __builtin_amdgcn_global_load_lds(
                (const __attribute__((address_space(1))) void*)g,
                (__attribute__((address_space(3))) void*)((char*)As + s * 4096 + w * 1024),
                16, 0, 0);
        }
        #pragma unroll
        for (int s = 0; s < BN / 64; s++) {
            const ushort* g = W + (size_t)(col0 + s * 64 + srow) * K + k0 + scol;
            __builtin_amdgcn_global_load_lds(
                (const __attribute__((address_space(1))) void*)g,
                (__attribute__((address_space(3))) void*)((char*)Ws + s * 4096 + w * 1024),
                16, 0, 0);
        }
        __syncthreads();

        short8 a[FM], b[FN];
        #pragma unroll
        for (int m = 0; m < FM; m++)
            a[m] = *(const short8*)(As + (wr * WM + m * 16 + l15) * 32 + l16 * 8);
        #pragma unroll
        for (int n = 0; n < FN; n++)
            b[n] = *(const short8*)(Ws + (wc * WN + n * 16 + l15) * 32 + l16 * 8);
        #pragma unroll
        for (int m = 0; m < FM; m++)
            #pragma unroll
            for (int n = 0; n < FN; n++)
                acc[m][n] = __builtin_amdgcn_mfma_f32_16x16x32_bf16(a[m], b[n], acc[m][n], 0, 0, 0);
        __syncthreads();
    }

    #pragma unroll
    for (int m = 0; m < FM; m++) {
        const int r0 = row0 + wr * WM + m * 16 + l16 * 4;
        #pragma unroll
        for (int n = 0; n < FN; n++) {
            const int c = col0 + wc * WN + n * 16 + l15;
            const float bv = BIAS ? bias[c] : 0.f;
            #pragma unroll
            for (int q = 0; q < 4; q++) {
                const int r = r0 + q;
                float v = acc[m][n][q] + bv;
                if (ACT == 1) v = softplus_f(v);
                else if (ACT == 2) v = gelu_f(v);
                if (RES) v += res[(size_t)r * ldr + c];
                if (OUTBF) ((ushort*)Cout)[(size_t)r * ldc + c] = f2bf(v);
                else       ((float*)Cout)[(size_t)r * ldc + c] = v;
            }
        }
    }
}

// ---------------- x_proj split-K MFMA: part[k] = xcb @ Wxb^T (K-chunk) ----------------
__global__ __launch_bounds__(256)
void xproj_split_kernel(const ushort* __restrict__ A,   // [2048][2048] bf16
                        const ushort* __restrict__ W,   // [96][2048] bf16
                        float* __restrict__ part) {     // [XKSPLIT][2048][96]
    __shared__ __align__(16) ushort As[128 * 64];  // row stride 64
    __shared__ __align__(16) ushort Bs[96 * 64];
    const int tid = threadIdx.x;
    const int lane = tid & 63, w = tid >> 6;
    const int l16 = lane >> 4, l15 = lane & 15;
    const int kbase = blockIdx.x * (D_INNER / XKSPLIT);   // *128
    const int row0 = blockIdx.y * 128;
    const int srow = tid >> 3;        // 0..31
    const int scol = (tid & 7) * 8;   // 0..56

    f32x4 acc[2][6] = {};

    for (int k0 = 0; k0 < D_INNER / XKSPLIT; k0 += 64) {
        #pragma unroll
        for (int s = 0; s < 4; s++) {
            const ushort* g = A + (size_t)(row0 + s * 32 + srow) * D_INNER + kbase + k0 + scol;
            __builtin_amdgcn_global_load_lds(
                (const __attribute__((address_space(1))) void*)g,
                (__attribute__((address_space(3))) void*)((char*)As + s * 4096 + w * 1024),
                16, 0, 0);
        }
        #pragma unroll
        for (int s = 0; s < 3; s++) {
            const ushort* g = W + (size_t)(s * 32 + srow) * D_INNER + kbase + k0 + scol;
            __builtin_amdgcn_global_load_lds(
                (const __attribute__((address_space(1))) void*)g,
                (__attribute__((address_space(3))) void*)((char*)Bs + s * 4096 + w * 1024),
                16, 0, 0);
        }
        __syncthreads();
        #pragma unroll
        for (int ks = 0; ks < 2; ks++) {
            short8 a[2], b[6];
            #pragma unroll
            for (int m = 0; m < 2; m++)
                a[m] = *(const short8*)(As + (w * 32 + m * 16 + l15) * 64 + ks * 32 + l16 * 8);
            #pragma unroll
            for (int n = 0; n < 6; n++)
                b[n] = *(const short8*)(Bs + (n * 16 + l15) * 64 + ks * 32 + l16 * 8);
            #pragma unroll
            for (int m = 0; m < 2; m++)
                #pragma unroll
                for (int n = 0; n < 6; n++)
                    acc[m][n] = __builtin_amdgcn_mfma_f32_16x16x32_bf16(a[m], b[n], acc[m][n], 0, 0, 0);
        }
        __syncthreads();
    }

    float* p = part + (size_t)blockIdx.x * D_INNER * NBC;
    #pragma unroll
    for (int m = 0; m < 2; m++) {
        const int r0 = row0 + w * 32 + m * 16 + l16 * 4;
        #pragma unroll
        for (int n = 0; n < 6; n++) {
            const int c = n * 16 + l15;
            #pragma unroll
            for (int q = 0; q < 4; q++)
                p[(size_t)(r0 + q) * NBC + c] = acc[m][n][q];
        }
    }
}

// reduce 16 K-slices -> dbc fp32; also emit bf16 of dt columns (c<64)
__global__ void xproj_reduce_kernel(const float* __restrict__ part,
                                    float* __restrict__ dbc, ushort* __restrict__ dtin_b) {
    int i = blockIdx.x * 256 + threadIdx.x;   // 2048*96
    if (i >= D_INNER * NBC) return;
    float s = 0.f;
    #pragma unroll
    for (int k = 0; k < XKSPLIT; k++) s += part[(size_t)k * D_INNER * NBC + i];
    dbc[i] = s;
    int r = i / NBC, c = i - r * NBC;
    if (c < DT_RANK) dtin_b[r * DT_RANK + c] = f2bf(s);
}

// ---------------- causal depthwise conv (k=4) + silu; bf16 in, fp32+bf16 out ----------------
__global__ void conv_silu_kernel(const ushort* __restrict__ xzb, const float* __restrict__ cw,
                                 const float* __restrict__ cb, float* __restrict__ xc,
                                 ushort* __restrict__ xcb) {
    int idx = blockIdx.x * 256 + threadIdx.x;      // TOK*D_INNER
    int c  = idx & (D_INNER - 1);
    int bt = idx >> 11;
    int b  = bt >> 10;
    int t  = bt & (SEQ - 1);
    float acc = cb[c];
    #pragma unroll
    for (int j = 0; j < 4; j++) {
        int tt = t - 3 + j;
        if (tt >= 0) acc += cw[c*4 + j] * bf2f(xzb[((size_t)(b*SEQ + tt)) * 4096 + c]);
    }
    float s = silu_f(acc);
    xc[idx] = s;
    xcb[idx] = f2bf(s);
}

// ---------------- chunked selective scan ----------------
__global__ void scan_chunk_kernel(const float* __restrict__ dt, const float* __restrict__ dbc,
                                  const float* __restrict__ xc, const float* __restrict__ A_log,
                                  float* __restrict__ chunkA, float* __restrict__ chunkH) {
    int idx = blockIdx.x * 256 + threadIdx.x;   // B*NCH*D_INNER
    int d = idx & (D_INNER - 1);
    int r = idx >> 11;
    int c = r & (NCH - 1);
    int b = r >> 5;
    float Arow[D_STATE];
    #pragma unroll
    for (int n = 0; n < D_STATE; n++) Arow[n] = -expf(A_log[d*D_STATE + n]);
    float h[D_STATE] = {};
    float ap[D_STATE];
    #pragma unroll
    for (int n = 0; n < D_STATE; n++) ap[n] = 1.f;
    const size_t rbase = (size_t)(b * SEQ + c * CS);
    for (int t = 0; t < CS; t++) {
        size_t row = rbase + t;
        float dtv = dt[row * D_INNER + d];
        float xv  = xc[row * D_INNER + d];
        const float* bc = dbc + row * NBC + DT_RANK;
        float dtx = dtv * xv;
        #pragma unroll
        for (int n = 0; n < D_STATE; n++) {
            float dA = expf(dtv * Arow[n]);
            ap[n] *= dA;
            h[n] = dA * h[n] + dtx * bc[n];
        }
    }
    size_t obase = ((size_t)(b * NCH + c) * D_STATE) * D_INNER + d;
    #pragma unroll
    for (int n = 0; n < D_STATE; n++) {
        chunkA[obase + (size_t)n * D_INNER] = ap[n];
        chunkH[obase + (size_t)n * D_INNER] = h[n];
    }
}

__global__ void scan_combine_kernel(const float* __restrict__ chunkA, float* __restrict__ chunkH) {
    int idx = blockIdx.x * 256 + threadIdx.x;   // B*D_STATE*D_INNER
    int d = idx & (D_INNER - 1);
    int r = idx >> 11;
    int n = r & (D_STATE - 1);
    int b = r >> 4;
    float h = 0.f;
    for (int c = 0; c < NCH; c++) {
        size_t o = ((size_t)((b * NCH + c) * D_STATE + n)) * D_INNER + d;
        float a  = chunkA[o];
        float hl = chunkH[o];
        chunkH[o] = h;
        h = a * h + hl;
    }
}

__global__ void scan_final_kernel(const float* __restrict__ dt, const float* __restrict__ dbc,
                                  const float* __restrict__ xc, const float* __restrict__ A_log,
                                  const float* __restrict__ chunkH, float* __restrict__ y) {
    int idx = blockIdx.x * 256 + threadIdx.x;   // B*NCH*D_INNER
    int d = idx & (D_INNER - 1);
    int r = idx >> 11;
    int c = r & (NCH - 1);
    int b = r >> 5;
    float Arow[D_STATE];
    #pragma unroll
    for (int n = 0; n < D_STATE; n++) Arow[n] = -expf(A_log[d*D_STATE + n]);
    float h[D_STATE];
    size_t obase = ((size_t)(b * NCH + c) * D_STATE) * D_INNER + d;
    #pragma unroll
    for (int n = 0; n < D_STATE; n++) h[n] = chunkH[obase + (size_t)n * D_INNER];
    const size_t rbase = (size_t)(b * SEQ + c * CS);
    for (int t = 0; t < CS; t++) {
        size_t row = rbase + t;
        float dtv = dt[row * D_INNER + d];
        float xv  = xc[row * D_INNER + d];
        const float* bc = dbc + row * NBC + DT_RANK;
        float dtx = dtv * xv;
        float yv = 0.f;
        #pragma unroll
        for (int n = 0; n < D_STATE; n++) {
            float dA = expf(dtv * Arow[n]);
            h[n] = dA * h[n] + dtx * bc[n];
            yv += h[n] * bc[D_STATE + n];
        }
        y[row * D_INNER + d] = yv;
    }
}

// ---------------- gating -> bf16: yb = (y + xc*D) * silu(z), z from bf16 xz ----------------
__global__ void gate_kernel(const float* __restrict__ y_in, const float* __restrict__ xc,
                            const ushort* __restrict__ xzb, const float* __restrict__ Dp,
                            ushort* __restrict__ y_out) {
    int idx = blockIdx.x * 256 + threadIdx.x;   // TOK*D_INNER
    int c   = idx & (D_INNER - 1);
    int row = idx >> 11;
    float z = bf2f(xzb[(size_t)row * 4096 + 2048 + c]);
    y_out[idx] = f2bf((y_in[idx] + xc[idx] * Dp[c]) * silu_f(z));
}

// ---------------- launch ----------------
extern "C" void kernel_launch(void* const* d_in, const int* in_sizes, int n_in,
                              void* d_out, int out_size, void* d_ws, size_t ws_size,
                              hipStream_t stream) {
    const float* x    = (const float*)d_in[0];
    const float* n1g  = (const float*)d_in[1];
    const float* n1b  = (const float*)d_in[2];
    const float* Wp   = (const float*)d_in[3];
    const float* cw   = (const float*)d_in[4];
    const float* cb   = (const float*)d_in[5];
    const float* Wx   = (const float*)d_in[6];
    const float* Wdt  = (const float*)d_in[7];
    const float* bdt  = (const float*)d_in[8];
    const float* Alog = (const float*)d_in[9];
    const float* Dp   = (const float*)d_in[10];
    const float* Wo   = (const float*)d_in[11];
    const float* n2g  = (const float*)d_in[12];
    const float* n2b  = (const float*)d_in[13];
    const float* W1   = (const float*)d_in[14];
    const float* b1   = (const float*)d_in[15];
    const float* W2   = (const float*)d_in[16];
    const float* b2   = (const float*)d_in[17];
    float* out = (float*)d_out;
    float* ws  = (float*)d_ws;

    const size_t M1 = 1024 * 1024;
    // workspace layout (float units) — non-overlapping map:
    //  [0,4M)        xzb  (bf16 2048x4096)
    //  [4M,8M)       xc   (fp32)
    //  [8M,10M)      xcb  (bf16 2048x2048)
    //  [10M,14M)     dtb  (fp32)
    //  [14M,18M)     part (3M) -> y (4M) -> hbuf (2M)   [sequential reuse]
    //  [18M,18M+196608)          dbc (fp32 2048x96)
    //  [18M+262144,18M+327680)   dtin_b (bf16 2048x64)
    //  [18M+524288,18M+1572864)  xnb/mb (bf16 2048x1024)
    //  [20M,22M)     yb/t1b (bf16 2048x2048)
    //  [22M,24M)     Wpb -> chunkA (fp32, reuse after in_proj)
    //  [24M,25M)     Wob
    //  [25M,26M)     W1b
    //  [26M,27M)     W2b
    //  [27M,27M+98304)           Wxb  (bf16 96x2048)
    //  [27M+131072,27M+196608)   Wdtb (bf16 2048x64)
    ushort* xzb   = (ushort*)ws;
    float*  xc    = ws + 4*M1;
    ushort* xcb   = (ushort*)(ws + 8*M1);
    float*  dtb   = ws + 10*M1;
    float*  y     = ws + 14*M1;
    float*  part  = y;
    float*  hbuf  = y;
    float*  dbc   = ws + 18*M1;
    ushort* dtin_b= (ushort*)(ws + 18*M1 + 262144);
    ushort* xnb   = (ushort*)(ws + 18*M1 + 524288);
    ushort* mb    = xnb;
    ushort* yb    = (ushort*)(ws + 20*M1);
    ushort* t1b   = yb;
    ushort* Wpb   = (ushort*)(ws + 22*M1);
    float*  chunkA= ws + 22*M1;
    ushort* Wob   = (ushort*)(ws + 24*M1);
    ushort* W1b   = (ushort*)(ws + 25*M1);
    ushort* W2b   = (ushort*)(ws + 26*M1);
    ushort* Wxb   = (ushort*)(ws + 27*M1);            // moved: was aliased with xnb
    ushort* Wdtb  = (ushort*)(ws + 27*M1 + 131072);   // moved: was aliased with xnb
    float*  chunkH = out;   // 2M fp32, overwritten by final GEMM (step 11)

    // 0. all weight converts in one launch
    convert_weights_kernel<<<(2703360 + 255)/256, 256, 0, stream>>>(
        Wp, Wo, W1, W2, Wx, Wdt, Wpb, Wob, W1b, W2b, Wxb, Wdtb);

    // 1. LN1 -> bf16
    ln_bf16_kernel<<<TOK, 256, 0, stream>>>(x, n1g, n1b, xnb);
    // 2. in_proj (MFMA) -> bf16 xz:  M=2048 N=4096 K=1024
    mfma_gemm<128,128,0,false,false,true><<<dim3(4096/128, 2048/128), 256, 0, stream>>>(
        xnb, Wpb, nullptr, nullptr, 0, xzb, 2*D_INNER, D_MODEL);
    // 3. conv + silu -> xc fp32 + xcb bf16
    conv_silu_kernel<<<TOK*D_INNER/256, 256, 0, stream>>>(xzb, cw, cb, xc, xcb);
    // 4. x_proj split-K MFMA + reduce -> dbc fp32, dtin_b bf16
    xproj_split_kernel<<<dim3(XKSPLIT, 2048/128), 256, 0, stream>>>(xcb, Wxb, part);
    xproj_reduce_kernel<<<(D_INNER*NBC + 255)/256, 256, 0, stream>>>(part, dbc, dtin_b);
    // 5. dt_proj (MFMA, softplus): M=2048 N=2048 K=64
    mfma_gemm<128,128,1,true,false,false><<<dim3(2048/128, 2048/128), 256, 0, stream>>>(
        dtin_b, Wdtb, bdt, nullptr, 0, dtb, D_INNER, DT_RANK);
    // 6. chunked selective scan
    scan_chunk_kernel<<<BATCH*NCH*D_INNER/256, 256, 0, stream>>>(dtb, dbc, xc, Alog, chunkA, chunkH);
    scan_combine_kernel<<<BATCH*D_STATE*D_INNER/256, 256, 0, stream>>>(chunkA, chunkH);
    scan_final_kernel<<<BATCH*NCH*D_INNER/256, 256, 0, stream>>>(dtb, dbc, xc, Alog, chunkH, y);
    // 7. gate -> bf16
    gate_kernel<<<TOK*D_INNER/256, 256, 0, stream>>>(y, xc, xzb, Dp, yb);
    // 8. out_proj (MFMA) + residual: hbuf = x + yb @ Wob^T
    mfma_gemm<128,64,0,false,true,false><<<dim3(1024/64, 2048/128), 256, 0, stream>>>(
        yb, Wob, nullptr, x, D_MODEL, hbuf, D_MODEL, D_INNER);
    // 9. LN2 -> bf16
    ln_bf16_kernel<<<TOK, 256, 0, stream>>>(hbuf, n2g, n2b, mb);
    // 10. mlp1 (MFMA, gelu) -> bf16
    mfma_gemm<128,128,2,true,false,true><<<dim3(2048/128, 2048/128), 256, 0, stream>>>(
        mb, W1b, b1, nullptr, 0, t1b, D_INNER, D_MODEL);
    // 11. mlp2 (MFMA) + bias + residual -> out
    mfma_gemm<128,64,0,true,true,false><<<dim3(1024/64, 2048/128), 256, 0, stream>>>(
        t1b, W2b, b2, hbuf, D_MODEL, out, D_MODEL, D_INNER);
}

// Round 6
// 270.319 us; speedup vs baseline: 6.3427x; 1.1801x over previous
//
#include <hip/hip_runtime.h>
#include <math.h>

#define D_MODEL 1024
#define D_INNER 2048
#define DT_RANK 64
#define D_STATE 16
#define NBC 96   // DT_RANK + 2*D_STATE
#define BATCH 2
#define SEQ 1024
#define TOK (BATCH*SEQ)  // 2048
#define CS 32            // scan chunk size
#define NCH 32           // chunks per sequence
#define XKSPLIT 16       // x_proj K-split

typedef __attribute__((ext_vector_type(8))) short short8;
typedef __attribute__((ext_vector_type(4))) float f32x4;

// ---------------- device helpers ----------------
__device__ __forceinline__ float softplus_f(float x) {
    return (x > 20.0f) ? x : log1pf(__expf(x));
}
__device__ __forceinline__ float gelu_f(float x) {
    return 0.5f * x * (1.0f + erff(x * 0.70710678118654752f));
}
__device__ __forceinline__ float silu_f(float x) {
    return x / (1.0f + __expf(-x));
}
__device__ __forceinline__ ushort f2bf(float f) {   // fp32 -> bf16 RNE
    unsigned u = __float_as_uint(f);
    unsigned r = (u + 0x7fffu + ((u >> 16) & 1u)) >> 16;
    return (ushort)r;
}
__device__ __forceinline__ float bf2f(ushort u) {
    return __uint_as_float(((unsigned)u) << 16);
}

// ---------------- fused weight fp32->bf16 convert (all 6 weights, 1 launch) ----------------
__global__ void convert_weights_kernel(const float* __restrict__ Wp, const float* __restrict__ Wo,
                                       const float* __restrict__ W1, const float* __restrict__ W2,
                                       const float* __restrict__ Wx, const float* __restrict__ Wdt,
                                       ushort* __restrict__ Wpb, ushort* __restrict__ Wob,
                                       ushort* __restrict__ W1b, ushort* __restrict__ W2b,
                                       ushort* __restrict__ Wxb, ushort* __restrict__ Wdtb) {
    int i = blockIdx.x * 256 + threadIdx.x;  // float4 index
    const float* src; ushort* dst; int off;
    if      (i < 1048576) { src = Wp;  dst = Wpb;  off = i; }
    else if (i < 1572864) { src = Wo;  dst = Wob;  off = i - 1048576; }
    else if (i < 2097152) { src = W1;  dst = W1b;  off = i - 1572864; }
    else if (i < 2621440) { src = W2;  dst = W2b;  off = i - 2097152; }
    else if (i < 2670592) { src = Wx;  dst = Wxb;  off = i - 2621440; }
    else if (i < 2703360) { src = Wdt; dst = Wdtb; off = i - 2670592; }
    else return;
    float4 v = ((const float4*)src)[off];
    ushort4 o;
    o.x = f2bf(v.x); o.y = f2bf(v.y); o.z = f2bf(v.z); o.w = f2bf(v.w);
    ((ushort4*)dst)[off] = o;
}

// ---------------- LayerNorm -> bf16 out ----------------
__global__ void ln_bf16_kernel(const float* __restrict__ x, const float* __restrict__ g,
                               const float* __restrict__ b, ushort* __restrict__ out) {
    int row = blockIdx.x;
    const float* xr = x + (size_t)row * D_MODEL;
    ushort* outr = out + (size_t)row * D_MODEL;
    int tid = threadIdx.x;
    float4 v = ((const float4*)xr)[tid];
    float s  = v.x + v.y + v.z + v.w;
    float sq = v.x*v.x + v.y*v.y + v.z*v.z + v.w*v.w;
    #pragma unroll
    for (int o = 32; o > 0; o >>= 1) {
        s  += __shfl_down(s,  o);
        sq += __shfl_down(sq, o);
    }
    __shared__ float ss[4], ssq[4];
    int wid = tid >> 6, lane = tid & 63;
    if (lane == 0) { ss[wid] = s; ssq[wid] = sq; }
    __syncthreads();
    if (tid == 0) {
        float a = 0.f, c = 0.f;
        for (int i = 0; i < 4; i++) { a += ss[i]; c += ssq[i]; }
        ss[0] = a; ssq[0] = c;
    }
    __syncthreads();
    float mean = ss[0] * (1.0f / D_MODEL);
    float var  = ssq[0] * (1.0f / D_MODEL) - mean * mean;
    float rstd = rsqrtf(var + 1e-5f);
    float4 gg = ((const float4*)g)[tid];
    float4 bb = ((const float4*)b)[tid];
    ushort4 o;
    o.x = f2bf((v.x - mean) * rstd * gg.x + bb.x);
    o.y = f2bf((v.y - mean) * rstd * gg.y + bb.y);
    o.z = f2bf((v.z - mean) * rstd * gg.z + bb.z);
    o.w = f2bf((v.w - mean) * rstd * gg.w + bb.w);
    ((ushort4*)outr)[tid] = o;
}

// ---------------- bf16 MFMA GEMM: C = act(A @ W^T [+bias]) [+res] ----------------
// ACT: 0=none, 1=softplus, 2=gelu
template<int BM, int BN, int ACT, bool BIAS, bool RES, bool OUTBF>
__global__ __launch_bounds__(256)
void mfma_gemm(const ushort* __restrict__ A, const ushort* __restrict__ W,
               const float* __restrict__ bias,
               const float* __restrict__ res, int ldr,
               void* __restrict__ Cout, int ldc, int K) {
    constexpr int WM = BM / 2, WN = BN / 2, FM = WM / 16, FN = WN / 16;
    __shared__ __align__(16) ushort As[BM * 32];
    __shared__ __align__(16) ushort Ws[BN * 32];
    const int tid  = threadIdx.x;
    const int lane = tid & 63, w = tid >> 6;
    const int wr = w >> 1, wc = w & 1;
    const int row0 = blockIdx.y * BM, col0 = blockIdx.x * BN;
    const int l16 = lane >> 4, l15 = lane & 15;
    const int srow = tid >> 2;
    const int scol = (tid & 3) * 8;

    f32x4 acc[FM][FN] = {};

    for (int k0 = 0; k0 < K; k0 += 32) {
        #pragma unroll
        for (int s = 0; s < BM / 64; s++) {
            const ushort* g = A + (size_t)(row0 + s * 64 + srow) * K + k0 + scol;
            __builtin_amdgcn_global_load_lds(
                (const __attribute__((address_space(1))) void*)g,
                (__attribute__((address_space(3))) void*)((char*)As + s * 4096 + w * 1024),
                16, 0, 0);
        }
        #pragma unroll
        for (int s = 0; s < BN / 64; s++) {
            const ushort* g = W + (size_t)(col0 + s * 64 + srow) * K + k0 + scol;
            __builtin_amdgcn_global_load_lds(
                (const __attribute__((address_space(1))) void*)g,
                (__attribute__((address_space(3))) void*)((char*)Ws + s * 4096 + w * 1024),
                16, 0, 0);
        }
        __syncthreads();

        short8 a[FM], b[FN];
        #pragma unroll
        for (int m = 0; m < FM; m++)
            a[m] = *(const short8*)(As + (wr * WM + m * 16 + l15) * 32 + l16 * 8);
        #pragma unroll
        for (int n = 0; n < FN; n++)
            b[n] = *(const short8*)(Ws + (wc * WN + n * 16 + l15) * 32 + l16 * 8);
        #pragma unroll
        for (int m = 0; m < FM; m++)
            #pragma unroll
            for (int n = 0; n < FN; n++)
                acc[m][n] = __builtin_amdgcn_mfma_f32_16x16x32_bf16(a[m], b[n], acc[m][n], 0, 0, 0);
        __syncthreads();
    }

    #pragma unroll
    for (int m = 0; m < FM; m++) {
        const int r0 = row0 + wr * WM + m * 16 + l16 * 4;
        #pragma unroll
        for (int n = 0; n < FN; n++) {
            const int c = col0 + wc * WN + n * 16 + l15;
            const float bv = BIAS ? bias[c] : 0.f;
            #pragma unroll
            for (int q = 0; q < 4; q++) {
                const int r = r0 + q;
                float v = acc[m][n][q] + bv;
                if (ACT == 1) v = softplus_f(v);
                else if (ACT == 2) v = gelu_f(v);
                if (RES) v += res[(size_t)r * ldr + c];
                if (OUTBF) ((ushort*)Cout)[(size_t)r * ldc + c] = f2bf(v);
                else       ((float*)Cout)[(size_t)r * ldc + c] = v;
            }
        }
    }
}

// ---------------- x_proj split-K MFMA: part[k] = xcb @ Wxb^T (K-chunk) ----------------
__global__ __launch_bounds__(256)
void xproj_split_kernel(const ushort* __restrict__ A,   // [2048][2048] bf16
                        const ushort* __restrict__ W,   // [96][2048] bf16
                        float* __restrict__ part) {     // [XKSPLIT][2048][96]
    __shared__ __align__(16) ushort As[128 * 64];  // row stride 64
    __shared__ __align__(16) ushort Bs[96 * 64];
    const int tid = threadIdx.x;
    const int lane = tid & 63, w = tid >> 6;
    const int l16 = lane >> 4, l15 = lane & 15;
    const int kbase = blockIdx.x * (D_INNER / XKSPLIT);   // *128
    const int row0 = blockIdx.y * 128;
    const int srow = tid >> 3;        // 0..31
    const int scol = (tid & 7) * 8;   // 0..56

    f32x4 acc[2][6] = {};

    for (int k0 = 0; k0 < D_INNER / XKSPLIT; k0 += 64) {
        #pragma unroll
        for (int s = 0; s < 4; s++) {
            const ushort* g = A + (size_t)(row0 + s * 32 + srow) * D_INNER + kbase + k0 + scol;
            __builtin_amdgcn_global_load_lds(
                (const __attribute__((address_space(1))) void*)g,
                (__attribute__((address_space(3))) void*)((char*)As + s * 4096 + w * 1024),
                16, 0, 0);
        }
        #pragma unroll
        for (int s = 0; s < 3; s++) {
            const ushort* g = W + (size_t)(s * 32 + srow) * D_INNER + kbase + k0 + scol;
            __builtin_amdgcn_global_load_lds(
                (const __attribute__((address_space(1))) void*)g,
                (__attribute__((address_space(3))) void*)((char*)Bs + s * 4096 + w * 1024),
                16, 0, 0);
        }
        __syncthreads();
        #pragma unroll
        for (int ks = 0; ks < 2; ks++) {
            short8 a[2], b[6];
            #pragma unroll
            for (int m = 0; m < 2; m++)
                a[m] = *(const short8*)(As + (w * 32 + m * 16 + l15) * 64 + ks * 32 + l16 * 8);
            #pragma unroll
            for (int n = 0; n < 6; n++)
                b[n] = *(const short8*)(Bs + (n * 16 + l15) * 64 + ks * 32 + l16 * 8);
            #pragma unroll
            for (int m = 0; m < 2; m++)
                #pragma unroll
                for (int n = 0; n < 6; n++)
                    acc[m][n] = __builtin_amdgcn_mfma_f32_16x16x32_bf16(a[m], b[n], acc[m][n], 0, 0, 0);
        }
        __syncthreads();
    }

    float* p = part + (size_t)blockIdx.x * D_INNER * NBC;
    #pragma unroll
    for (int m = 0; m < 2; m++) {
        const int r0 = row0 + w * 32 + m * 16 + l16 * 4;
        #pragma unroll
        for (int n = 0; n < 6; n++) {
            const int c = n * 16 + l15;
            #pragma unroll
            for (int q = 0; q < 4; q++)
                p[(size_t)(r0 + q) * NBC + c] = acc[m][n][q];
        }
    }
}

// reduce 16 K-slices -> dbc fp32; also emit bf16 of dt columns (c<64)
__global__ void xproj_reduce_kernel(const float* __restrict__ part,
                                    float* __restrict__ dbc, ushort* __restrict__ dtin_b) {
    int i = blockIdx.x * 256 + threadIdx.x;   // 2048*96
    if (i >= D_INNER * NBC) return;
    float s = 0.f;
    #pragma unroll
    for (int k = 0; k < XKSPLIT; k++) s += part[(size_t)k * D_INNER * NBC + i];
    dbc[i] = s;
    int r = i / NBC, c = i - r * NBC;
    if (c < DT_RANK) dtin_b[r * DT_RANK + c] = f2bf(s);
}

// ---------------- causal depthwise conv (k=4) + silu; bf16 in, bf16 out ----------------
__global__ void conv_silu_kernel(const ushort* __restrict__ xzb, const float* __restrict__ cw,
                                 const float* __restrict__ cb, ushort* __restrict__ xcb) {
    int idx = blockIdx.x * 256 + threadIdx.x;      // TOK*D_INNER
    int c  = idx & (D_INNER - 1);
    int bt = idx >> 11;
    int b  = bt >> 10;
    int t  = bt & (SEQ - 1);
    float acc = cb[c];
    #pragma unroll
    for (int j = 0; j < 4; j++) {
        int tt = t - 3 + j;
        if (tt >= 0) acc += cw[c*4 + j] * bf2f(xzb[((size_t)(b*SEQ + tt)) * 4096 + c]);
    }
    xcb[idx] = f2bf(silu_f(acc));
}

// ---------------- chunked selective scan, n-split x4 ----------------
// thread <-> (b, chunk, d, ng): ng = 4-state group; lanes 4k..4k+3 share d.
// K1: local scan from h=0 -> chunkA (aProd), chunkH (hLocal), layout [b][c][n][d]
__global__ void scan_chunk_kernel(const float* __restrict__ dt, const float* __restrict__ dbc,
                                  const ushort* __restrict__ xcb, const float* __restrict__ A_log,
                                  float* __restrict__ chunkA, float* __restrict__ chunkH) {
    int idx = blockIdx.x * 256 + threadIdx.x;   // B*NCH*D_INNER*4 = 524288
    int ng = idx & 3;
    int d  = (idx >> 2) & (D_INNER - 1);
    int r  = idx >> 13;
    int c  = r & (NCH - 1);
    int b  = r >> 5;
    const int nb = ng * 4;
    float Arow[4];
    #pragma unroll
    for (int j = 0; j < 4; j++) Arow[j] = -__expf(A_log[d * D_STATE + nb + j]);
    float h[4] = {};
    float ap[4] = {1.f, 1.f, 1.f, 1.f};
    const size_t rbase = (size_t)(b * SEQ + c * CS);
    for (int t = 0; t < CS; t++) {
        size_t row = rbase + t;
        float dtv = dt[row * D_INNER + d];
        float xv  = bf2f(xcb[row * D_INNER + d]);
        const float* bc = dbc + row * NBC + DT_RANK;
        float dtx = dtv * xv;
        #pragma unroll
        for (int j = 0; j < 4; j++) {
            float dA = __expf(dtv * Arow[j]);
            ap[j] *= dA;
            h[j] = dA * h[j] + dtx * bc[nb + j];
        }
    }
    size_t obase = ((size_t)(b * NCH + c) * D_STATE + nb) * D_INNER + d;
    #pragma unroll
    for (int j = 0; j < 4; j++) {
        chunkA[obase + (size_t)j * D_INNER] = ap[j];
        chunkH[obase + (size_t)j * D_INNER] = h[j];
    }
}

// K2: per (b, n, d): compose chunk summaries serially; chunkH <- incoming state
__global__ void scan_combine_kernel(const float* __restrict__ chunkA, float* __restrict__ chunkH) {
    int idx = blockIdx.x * 256 + threadIdx.x;   // B*D_STATE*D_INNER
    int d = idx & (D_INNER - 1);
    int r = idx >> 11;
    int n = r & (D_STATE - 1);
    int b = r >> 4;
    float h = 0.f;
    for (int c = 0; c < NCH; c++) {
        size_t o = ((size_t)((b * NCH + c) * D_STATE + n)) * D_INNER + d;
        float a  = chunkA[o];
        float hl = chunkH[o];
        chunkH[o] = h;
        h = a * h + hl;
    }
}

// K3: re-run chunk seeded with hIn; fused gate: yb = bf16((y + xc*D) * silu(z))
__global__ void scan_final_kernel(const float* __restrict__ dt, const float* __restrict__ dbc,
                                  const ushort* __restrict__ xcb, const float* __restrict__ A_log,
                                  const float* __restrict__ chunkH, const ushort* __restrict__ xzb,
                                  const float* __restrict__ Dp, ushort* __restrict__ yb) {
    int idx = blockIdx.x * 256 + threadIdx.x;   // B*NCH*D_INNER*4
    int ng = idx & 3;
    int d  = (idx >> 2) & (D_INNER - 1);
    int r  = idx >> 13;
    int c  = r & (NCH - 1);
    int b  = r >> 5;
    const int nb = ng * 4;
    float Arow[4];
    #pragma unroll
    for (int j = 0; j < 4; j++) Arow[j] = -__expf(A_log[d * D_STATE + nb + j]);
    float h[4];
    size_t obase = ((size_t)(b * NCH + c) * D_STATE + nb) * D_INNER + d;
    #pragma unroll
    for (int j = 0; j < 4; j++) h[j] = chunkH[obase + (size_t)j * D_INNER];
    const float Dpv = Dp[d];
    const size_t rbase = (size_t)(b * SEQ + c * CS);
    for (int t = 0; t < CS; t++) {
        size_t row = rbase + t;
        float dtv = dt[row * D_INNER + d];
        float xv  = bf2f(xcb[row * D_INNER + d]);
        const float* bc = dbc + row * NBC + DT_RANK;
        float dtx = dtv * xv;
        float yv = 0.f;
        #pragma unroll
        for (int j = 0; j < 4; j++) {
            float dA = __expf(dtv * Arow[j]);
            h[j] = dA * h[j] + dtx * bc[nb + j];
            yv += h[j] * bc[D_STATE + nb + j];
        }
        yv += __shfl_xor(yv, 1);
        yv += __shfl_xor(yv, 2);
        if (ng == 0) {
            float z = bf2f(xzb[row * 4096 + 2048 + d]);
            yb[row * D_INNER + d] = f2bf((yv + xv * Dpv) * silu_f(z));
        }
    }
}

// ---------------- launch ----------------
extern "C" void kernel_launch(void* const* d_in, const int* in_sizes, int n_in,
                              void* d_out, int out_size, void* d_ws, size_t ws_size,
                              hipStream_t stream) {
    const float* x    = (const float*)d_in[0];
    const float* n1g  = (const float*)d_in[1];
    const float* n1b  = (const float*)d_in[2];
    const float* Wp   = (const float*)d_in[3];
    const float* cw   = (const float*)d_in[4];
    const float* cb   = (const float*)d_in[5];
    const float* Wx   = (const float*)d_in[6];
    const float* Wdt  = (const float*)d_in[7];
    const float* bdt  = (const float*)d_in[8];
    const float* Alog = (const float*)d_in[9];
    const float* Dp   = (const float*)d_in[10];
    const float* Wo   = (const float*)d_in[11];
    const float* n2g  = (const float*)d_in[12];
    const float* n2b  = (const float*)d_in[13];
    const float* W1   = (const float*)d_in[14];
    const float* b1   = (const float*)d_in[15];
    const float* W2   = (const float*)d_in[16];
    const float* b2   = (const float*)d_in[17];
    float* out = (float*)d_out;
    float* ws  = (float*)d_ws;

    const size_t M1 = 1024 * 1024;
    // workspace layout (float units) — non-overlapping map:
    //  [0,4M)        xzb  (bf16 2048x4096)
    //  [8M,10M)      xcb  (bf16 2048x2048)
    //  [10M,14M)     dtb  (fp32)
    //  [14M,18M)     part (3M) -> hbuf (2M)   [sequential reuse]
    //  [18M,18M+196608)          dbc (fp32 2048x96)
    //  [18M+262144,18M+327680)   dtin_b (bf16 2048x64)
    //  [18M+524288,18M+1572864)  xnb/mb (bf16 2048x1024)
    //  [20M,22M)     yb/t1b (bf16 2048x2048)
    //  [22M,24M)     Wpb -> chunkA (fp32, reuse after in_proj)
    //  [24M,25M)     Wob
    //  [25M,26M)     W1b
    //  [26M,27M)     W2b
    //  [27M,27M+98304)           Wxb  (bf16 96x2048)
    //  [27M+131072,27M+196608)   Wdtb (bf16 2048x64)
    ushort* xzb   = (ushort*)ws;
    ushort* xcb   = (ushort*)(ws + 8*M1);
    float*  dtb   = ws + 10*M1;
    float*  part  = ws + 14*M1;
    float*  hbuf  = ws + 14*M1;
    float*  dbc   = ws + 18*M1;
    ushort* dtin_b= (ushort*)(ws + 18*M1 + 262144);
    ushort* xnb   = (ushort*)(ws + 18*M1 + 524288);
    ushort* mb    = xnb;
    ushort* yb    = (ushort*)(ws + 20*M1);
    ushort* t1b   = yb;
    ushort* Wpb   = (ushort*)(ws + 22*M1);
    float*  chunkA= ws + 22*M1;
    ushort* Wob   = (ushort*)(ws + 24*M1);
    ushort* W1b   = (ushort*)(ws + 25*M1);
    ushort* W2b   = (ushort*)(ws + 26*M1);
    ushort* Wxb   = (ushort*)(ws + 27*M1);
    ushort* Wdtb  = (ushort*)(ws + 27*M1 + 131072);
    float*  chunkH = out;   // 2M fp32, overwritten by final GEMM (step 11)

    // 0. all weight converts in one launch
    convert_weights_kernel<<<(2703360 + 255)/256, 256, 0, stream>>>(
        Wp, Wo, W1, W2, Wx, Wdt, Wpb, Wob, W1b, W2b, Wxb, Wdtb);

    // 1. LN1 -> bf16
    ln_bf16_kernel<<<TOK, 256, 0, stream>>>(x, n1g, n1b, xnb);
    // 2. in_proj (MFMA) -> bf16 xz:  M=2048 N=4096 K=1024
    mfma_gemm<128,128,0,false,false,true><<<dim3(4096/128, 2048/128), 256, 0, stream>>>(
        xnb, Wpb, nullptr, nullptr, 0, xzb, 2*D_INNER, D_MODEL);
    // 3. conv + silu -> xcb bf16
    conv_silu_kernel<<<TOK*D_INNER/256, 256, 0, stream>>>(xzb, cw, cb, xcb);
    // 4. x_proj split-K MFMA + reduce -> dbc fp32, dtin_b bf16
    xproj_split_kernel<<<dim3(XKSPLIT, 2048/128), 256, 0, stream>>>(xcb, Wxb, part);
    xproj_reduce_kernel<<<(D_INNER*NBC + 255)/256, 256, 0, stream>>>(part, dbc, dtin_b);
    // 5. dt_proj (MFMA, softplus): M=2048 N=2048 K=64
    mfma_gemm<128,128,1,true,false,false><<<dim3(2048/128, 2048/128), 256, 0, stream>>>(
        dtin_b, Wdtb, bdt, nullptr, 0, dtb, D_INNER, DT_RANK);
    // 6. chunked selective scan (n-split x4), gate fused into final
    scan_chunk_kernel<<<BATCH*NCH*D_INNER*4/256, 256, 0, stream>>>(dtb, dbc, xcb, Alog, chunkA, chunkH);
    scan_combine_kernel<<<BATCH*D_STATE*D_INNER/256, 256, 0, stream>>>(chunkA, chunkH);
    scan_final_kernel<<<BATCH*NCH*D_INNER*4/256, 256, 0, stream>>>(dtb, dbc, xcb, Alog, chunkH,
                                                                   xzb, Dp, yb);
    // 8. out_proj (MFMA) + residual: hbuf = x + yb @ Wob^T
    mfma_gemm<128,64,0,false,true,false><<<dim3(1024/64, 2048/128), 256, 0, stream>>>(
        yb, Wob, nullptr, x, D_MODEL, hbuf, D_MODEL, D_INNER);
    // 9. LN2 -> bf16
    ln_bf16_kernel<<<TOK, 256, 0, stream>>>(hbuf, n2g, n2b, mb);
    // 10. mlp1 (MFMA, gelu) -> bf16
    mfma_gemm<128,128,2,true,false,true><<<dim3(2048/128, 2048/128), 256, 0, stream>>>(
        mb, W1b, b1, nullptr, 0, t1b, D_INNER, D_MODEL);
    // 11. mlp2 (MFMA) + bias + residual -> out
    mfma_gemm<128,64,0,true,true,false><<<dim3(1024/64, 2048/128), 256, 0, stream>>>(
        t1b, W2b, b2, hbuf, D_MODEL, out, D_MODEL, D_INNER);
}